// Round 12
// baseline (62.554 us; speedup 1.0000x reference)
//
#include <hip/hip_runtime.h>
#include <math.h>

#define D 256
#define NRULES 1024
#define TPB 8        // tokens per pass over a rule matrix
#define NTOKMAX 2048 // B*S for this problem

// ---------------- prep: pure map, no atomics, no memset ----------------
__global__ void prep_kernel(const int* __restrict__ token_ids,
                            const int* __restrict__ token_rules,
                            int ntok, int* __restrict__ rtok) {
    const int i = blockIdx.x * blockDim.x + threadIdx.x;
    if (i < ntok) rtok[i] = token_rules[token_ids[i]];
}

// ---------------- one TPB-pass over a rule matrix (R5 structure) ----------------
// 4 waves; wave owns 64-col quarter; rr=lane>>4 row subgroup (rows 4i+rr);
// lockstep full 1KB rows across the 4 waves.
template <int CR>
__device__ __forceinline__ void rule_pass(
    const float* __restrict__ M,
    const float* __restrict__ hidden,
    const int* __restrict__ toks,      // LDS token list
    int base, int c,                   // live tokens this pass, c <= CR
    bool trailing_barrier,
    int wave, int lane, int rr, int col,
    float (*__restrict__ h_lds)[D], float* __restrict__ sq_lds,
    float* __restrict__ out)
{
    // stage h rows as float4: wave j stages token row base+j (64 lanes x 16B)
    for (int j = wave; j < CR; j += 4) {
        float4 v = {0.f, 0.f, 0.f, 0.f};
        if (j < c)
            v = *reinterpret_cast<const float4*>(
                &hidden[(size_t)toks[base + j] * D + (lane << 2)]);
        *reinterpret_cast<float4*>(&h_lds[j][lane << 2]) = v;
    }
    __syncthreads();

    float4 acc[CR];
    #pragma unroll
    for (int j = 0; j < CR; ++j) acc[j] = float4{0.f, 0.f, 0.f, 0.f};
    float s0 = 0.f, s1 = 0.f, s2 = 0.f, s3 = 0.f;  // independent fro chains

    #pragma unroll 8
    for (int i = 0; i < 64; ++i) {
        const int d = (i << 2) + rr;
        const float4 m = *reinterpret_cast<const float4*>(M + (size_t)d * D + col);
        s0 = fmaf(m.x, m.x, s0);
        s1 = fmaf(m.y, m.y, s1);
        s2 = fmaf(m.z, m.z, s2);
        s3 = fmaf(m.w, m.w, s3);
        #pragma unroll
        for (int j = 0; j < CR; ++j) {
            const float h = h_lds[j][d];  // 4 addrs/wave, x16 broadcast — conflict-free
            acc[j].x = fmaf(h, m.x, acc[j].x);
            acc[j].y = fmaf(h, m.y, acc[j].y);
            acc[j].z = fmaf(h, m.z, acc[j].z);
            acc[j].w = fmaf(h, m.w, acc[j].w);
        }
    }

    // Frobenius: wave reduce, park per wave (same value every pass)
    float sq = (s0 + s1) + (s2 + s3);
    #pragma unroll
    for (int off = 32; off > 0; off >>= 1)
        sq += __shfl_down(sq, off, 64);
    if (lane == 0) sq_lds[wave] = sq;

    // butterfly over the 4 row-subgroups: every lane gets full column sums
    #pragma unroll
    for (int j = 0; j < CR; ++j) {
        #pragma unroll
        for (int mask = 16; mask < 64; mask <<= 1) {
            acc[j].x += __shfl_xor(acc[j].x, mask, 64);
            acc[j].y += __shfl_xor(acc[j].y, mask, 64);
            acc[j].z += __shfl_xor(acc[j].z, mask, 64);
            acc[j].w += __shfl_xor(acc[j].w, mask, 64);
        }
    }
    __syncthreads();  // sq_lds visible to all

    const float fro2 = sq_lds[0] + sq_lds[1] + sq_lds[2] + sq_lds[3];
    const float inv  = 1.0f / fmaxf(sqrtf(fro2), 1e-12f);

    // subgroup (j&3) writes token j's quarter (16 lanes x 16B contiguous)
    #pragma unroll
    for (int j = 0; j < CR; ++j) {
        if (j < c && rr == (j & 3)) {
            const int tok = toks[base + j];
            float4 o;
            o.x = acc[j].x * inv; o.y = acc[j].y * inv;
            o.z = acc[j].z * inv; o.w = acc[j].w * inv;
            *reinterpret_cast<float4*>(&out[(size_t)tok * D + col]) = o;
        }
    }
    if (trailing_barrier) __syncthreads();  // protect h_lds for next pass
}

// ---------------- process: block b == rule b; block builds its own token list ----------------
__global__ __launch_bounds__(256) void process_kernel(
    const float* __restrict__ hidden,     // [NTOK, D]
    const float* __restrict__ rules,      // [NRULES, D, D]
    const int*   __restrict__ rtok,       // [ntok] rule of each token
    int ntok,
    float* __restrict__ out)              // [NTOK, D]
{
    const int b    = blockIdx.x;
    const int t    = threadIdx.x;
    const int wave = t >> 6;
    const int lane = t & 63;
    const int rr   = lane >> 4;
    const int col  = (wave << 6) + ((lane & 15) << 2);

    __shared__ int   toks[NTOKMAX];
    __shared__ int   cnt_lds;
    __shared__ float h_lds[TPB][D];
    __shared__ float sq_lds[4];

    if (t == 0) cnt_lds = 0;
    __syncthreads();

    // scan rtok (8KB, L2-broadcast across blocks) for tokens of rule b
    const int lim = (ntok < NTOKMAX) ? ntok : NTOKMAX;
    for (int i = t; i < lim; i += 256)
        if (rtok[i] == b) toks[atomicAdd(&cnt_lds, 1)] = i;
    __syncthreads();

    const int cnt = cnt_lds;
    if (cnt == 0) return;

    const float* __restrict__ M = rules + (size_t)b * D * D;

    for (int base = 0; base < cnt; base += TPB) {
        const int c = min(cnt - base, TPB);
        const bool more = (base + TPB < cnt);
        switch ((c == 1) ? 1 : (c == 2) ? 2 : (c <= 4) ? 4 : 8) {
            case 1:  rule_pass<1>(M, hidden, toks, base, c, more, wave, lane, rr, col, h_lds, sq_lds, out); break;
            case 2:  rule_pass<2>(M, hidden, toks, base, c, more, wave, lane, rr, col, h_lds, sq_lds, out); break;
            case 4:  rule_pass<4>(M, hidden, toks, base, c, more, wave, lane, rr, col, h_lds, sq_lds, out); break;
            default: rule_pass<8>(M, hidden, toks, base, c, more, wave, lane, rr, col, h_lds, sq_lds, out); break;
        }
    }
}

// ---------------- launcher ----------------
extern "C" void kernel_launch(void* const* d_in, const int* in_sizes, int n_in,
                              void* d_out, int out_size, void* d_ws, size_t ws_size,
                              hipStream_t stream) {
    const float* hidden      = (const float*)d_in[0];
    const int*   token_ids   = (const int*)d_in[1];
    const float* rules       = (const float*)d_in[2];
    const int*   token_rules = (const int*)d_in[3];
    float*       out         = (float*)d_out;

    const int ntok = in_sizes[1];  // B*S

    int* rtok = (int*)d_ws;        // ntok ints

    prep_kernel<<<(ntok + 255) / 256, 256, 0, stream>>>(
        token_ids, token_rules, ntok, rtok);
    process_kernel<<<NRULES, 256, 0, stream>>>(
        hidden, rules, rtok, ntok, out);
}